// Round 14
// baseline (1109.049 us; speedup 1.0000x reference)
//
#include <hip/hip_runtime.h>
#include <hip/hip_bf16.h>
#include <stdint.h>
#include <math.h>

// ---------------------------------------------------------------------------
// SymmetricRBM: CD loss, 10-step Gibbs, JAX-threefry-exact RNG.
// B=8192, V=H=1024. R13->R14: carry UNFLIPPED state x (v = u?x:1-x).
// Identity: v_branch = u*v+(1-u)(1-v) == x  -> EPI1 needs no u/colsum branch;
// x_new = Bern(sig(a+b)) is u-independent -> sampled inside the a=h@W^T gemm
// epilogue (EPI3) together with deterministic per-block row-partials
// (sum a, sum x*a, sum x*b); tiny u_row kernel finishes dE -> u_new.
// Deletes all 10 row_uv dispatches (48 MB each). gemm core frozen (R12).
// ---------------------------------------------------------------------------

static constexpr int Bn = 8192;
static constexpr int Vn = 1024;
static constexpr int Hn = 1024;
static constexpr int KSTEPS = 10;

typedef _Float16 f16;
typedef f16   f16x4 __attribute__((ext_vector_type(4)));
typedef f16   f16x8 __attribute__((ext_vector_type(8)));
typedef float f32x4 __attribute__((ext_vector_type(4)));

#define GLOBAL_LOAD_LDS16(g, l)                                              \
  __builtin_amdgcn_global_load_lds(                                          \
      (const __attribute__((address_space(1))) uint32_t*)(g),                \
      (__attribute__((address_space(3))) uint32_t*)(l), 16, 0, 0)

// ------------------------- Threefry-2x32 (JAX-exact) -----------------------
__device__ __forceinline__ uint32_t rotl32(uint32_t x, int d) {
  return (x << d) | (x >> (32 - d));
}

__device__ __forceinline__ void tf2x32(uint32_t k0, uint32_t k1,
                                       uint32_t x0, uint32_t x1,
                                       uint32_t& o0, uint32_t& o1) {
  uint32_t k2 = k0 ^ k1 ^ 0x1BD11BDAu;
#define TFR(r) { x0 += x1; x1 = rotl32(x1, (r)); x1 ^= x0; }
  x0 += k0; x1 += k1;
  TFR(13) TFR(15) TFR(26) TFR(6)
  x0 += k1; x1 += k2 + 1u;
  TFR(17) TFR(29) TFR(16) TFR(24)
  x0 += k2; x1 += k0 + 2u;
  TFR(13) TFR(15) TFR(26) TFR(6)
  x0 += k0; x1 += k1 + 3u;
  TFR(17) TFR(29) TFR(16) TFR(24)
  x0 += k1; x1 += k2 + 4u;
  TFR(13) TFR(15) TFR(26) TFR(6)
  x0 += k2; x1 += k0 + 5u;
#undef TFR
  o0 = x0; o1 = x1;
}

__device__ __forceinline__ float rng_u01(uint2 key, uint32_t idx) {
  uint32_t o0, o1;
  tf2x32(key.x, key.y, 0u, idx, o0, o1);
  uint32_t bits = o0 ^ o1;
  return __uint_as_float((bits >> 9) | 0x3F800000u) - 1.0f;
}

// fast Bernoulli accept: r01 < sigmoid(z)  <=>  r01*(1+exp(-z)) < 1
__device__ __forceinline__ float bern_fast(float z, float r01) {
  float e = __expf(-z);
  return (__builtin_fmaf(r01, e, r01) < 1.0f) ? 1.f : 0.f;
}
__device__ __forceinline__ float softplus_fast(float x) {
  return fmaxf(x, 0.f) + __logf(1.f + __expf(-fabsf(x)));
}

// ------------------------------- prep kernels ------------------------------
__global__ void prep_keys(const int* __restrict__ seedp, uint2* __restrict__ keys) {
  if (threadIdx.x != 0 || blockIdx.x != 0) return;
  uint32_t seed = (uint32_t)(*seedp);
  uint2 key = make_uint2(0u, seed);
  uint2 nk, kk;
  tf2x32(key.x, key.y, 0u, 0u, nk.x, nk.y);
  tf2x32(key.x, key.y, 0u, 1u, kk.x, kk.y);
  keys[0] = kk;   // k0
  key = nk;
  for (int s = 0; s < KSTEPS; ++s) {
    uint2 t0, t1, t2, t3;
    tf2x32(key.x, key.y, 0u, 0u, t0.x, t0.y);
    tf2x32(key.x, key.y, 0u, 1u, t1.x, t1.y);
    tf2x32(key.x, key.y, 0u, 2u, t2.x, t2.y);
    tf2x32(key.x, key.y, 0u, 3u, t3.x, t3.y);
    key = t0;
    keys[1 + 3*s] = t1;  // k1
    keys[2 + 3*s] = t2;  // k2
    keys[3 + 3*s] = t3;  // k3
  }
}

__global__ __launch_bounds__(256) void colsum_part(
    const float* __restrict__ W, float* __restrict__ part) {
  const int bx = blockIdx.x, t = threadIdx.x;
  float s0 = 0.f, s1 = 0.f, s2 = 0.f, s3 = 0.f;
#pragma unroll
  for (int r = 0; r < 16; ++r) {
    const float* row = W + (size_t)(bx * 16 + r) * Hn;
    s0 += row[t]; s1 += row[t + 256]; s2 += row[t + 512]; s3 += row[t + 768];
  }
  float* p = part + (size_t)bx * Hn;
  p[t] = s0; p[t + 256] = s1; p[t + 512] = s2; p[t + 768] = s3;
}

__global__ __launch_bounds__(256) void colsum_red(
    const float* __restrict__ part, float* __restrict__ cs) {
  const int col = blockIdx.x * 256 + threadIdx.x;
  float s = 0.f;
#pragma unroll
  for (int k = 0; k < 64; ++k) s += part[(size_t)k * Hn + col];
  cs[col] = s;
}

__global__ void bsum_k(const float* __restrict__ bvec, float* __restrict__ bs) {
  __shared__ float sb[4];
  float s = 0.f;
  for (int i = threadIdx.x; i < Vn; i += 256) s += bvec[i];
  for (int off = 32; off > 0; off >>= 1) s += __shfl_down(s, off, 64);
  int wv = threadIdx.x >> 6, ln = threadIdx.x & 63;
  if (ln == 0) sb[wv] = s;
  __syncthreads();
  if (threadIdx.x == 0) bs[0] = sb[0] + sb[1] + sb[2] + sb[3];
}

__global__ __launch_bounds__(256) void cast_W(
    const float* __restrict__ W, f16* __restrict__ Wf, f16* __restrict__ WTf) {
  __shared__ f16 tile[64][65];
  const int j0 = blockIdx.x * 64, i0 = blockIdx.y * 64;
  const int tx = threadIdx.x & 63, tg = threadIdx.x >> 6;
#pragma unroll 4
  for (int rr = 0; rr < 16; ++rr) {
    const int row = tg * 16 + rr;
    float w = W[(size_t)(i0 + row) * Hn + j0 + tx];
    f16 hw = (f16)w;
    Wf[(size_t)(i0 + row) * Hn + j0 + tx] = hw;
    tile[row][tx] = hw;
  }
  __syncthreads();
#pragma unroll 4
  for (int rr = 0; rr < 16; ++rr) {
    const int row = tg * 16 + rr;
    WTf[(size_t)(j0 + row) * Vn + i0 + tx] = tile[tx][row];
  }
}

__global__ void u0_init(const uint2* __restrict__ keys, float* __restrict__ u) {
  int b = blockIdx.x * 256 + threadIdx.x;
  float r01 = rng_u01(keys[0], (uint32_t)b);
  u[b] = (r01 < 0.5f) ? 1.f : 0.f;
}

// x0 = u0 ? v_data : 1 - v_data   (unflipped carry; v = u?x:1-x)
__global__ __launch_bounds__(256) void cast_vx(
    const float* __restrict__ vd, const float* __restrict__ u,
    f16* __restrict__ x) {
  const int idx = blockIdx.x * 256 + threadIdx.x;   // group of 4
  const int row = idx >> 8;
  const float uo = u[row];
  const float4 d = ((const float4*)vd)[idx];
  f16x4 o;
  if (uo > 0.5f) { o[0]=(f16)d.x; o[1]=(f16)d.y; o[2]=(f16)d.z; o[3]=(f16)d.w; }
  else { o[0]=(f16)(1.f-d.x); o[1]=(f16)(1.f-d.y); o[2]=(f16)(1.f-d.z); o[3]=(f16)(1.f-d.w); }
  *(f16x4*)(x + (size_t)idx * 4) = o;
}

// ------------------------- GEMM: 64x64 max-occupancy ------------------------
// Core frozen from R12 (43 us, 8 blocks/CU, 0 conflicts).
// EPI 0: store f16 C.
// EPI 1: h = Bern(sig(C + c))                       [v_branch == x identity]
// EPI 2: store C AND h (step-0 / F(v_data) fusion)
// EPI 3: a-epilogue: x_new = Bern(sig(C+b)); row-partials sum(a), sum(x*a),
//        sum(x*b) -> part arrays [32][Bn] (deterministic, no atomics).
template <int EPI>
__global__ __launch_bounds__(256, 8) void gemm_s(
    const f16* __restrict__ A, const f16* __restrict__ Bm,
    f16* __restrict__ outA, f16* __restrict__ outH,
    const f16* __restrict__ xold, f16* __restrict__ xnew,
    const float* __restrict__ bvec, const float* __restrict__ cvec,
    float* __restrict__ pA, float* __restrict__ pXA, float* __restrict__ pXB,
    const uint2* __restrict__ keys, int keyIdx)
{
  constexpr int N = 1024, K = 1024, BK = 64;
  __shared__ alignas(16) f16 As[64 * BK];   // 8 KB
  __shared__ alignas(16) f16 Bs[64 * BK];   // 8 KB

  const int t = threadIdx.x, wave = t >> 6, lane = t & 63;
  const int l15 = lane & 15, quad = lane >> 4;
  const int m0 = blockIdx.x * 64, n0 = blockIdx.y * 64;
  const int wm = (wave >> 1) * 32, wn = (wave & 1) * 32;

  const int rbase = lane >> 3;
  const int gch   = (lane & 7) ^ rbase;
  const f16* gA = A  + (size_t)(m0 + wave * 16 + rbase) * K + gch * 8;
  const f16* gB = Bm + (size_t)(n0 + wave * 16 + rbase) * K + gch * 8;
  f16* lA = As + wave * 16 * BK;
  f16* lB = Bs + wave * 16 * BK;

  const int swz = l15 & 7;
  const int oA  = (wm + l15) * BK;
  const int oB  = (wn + l15) * BK;

  f32x4 acc[2][2] = {};

  for (int k0 = 0; k0 < K; k0 += BK) {
    GLOBAL_LOAD_LDS16(gA + k0,         lA);
    GLOBAL_LOAD_LDS16(gA + k0 + 8 * K, lA + 8 * BK);
    GLOBAL_LOAD_LDS16(gB + k0,         lB);
    GLOBAL_LOAD_LDS16(gB + k0 + 8 * K, lB + 8 * BK);
    __syncthreads();

#pragma unroll
    for (int kc = 0; kc < 2; ++kc) {
      const int fc = ((kc * 4 + quad) ^ swz) * 8;
      f16x8 af[2], bf[2];
#pragma unroll
      for (int i = 0; i < 2; ++i) {
        af[i] = *(const f16x8*)(&As[oA + i * 16 * BK + fc]);
        bf[i] = *(const f16x8*)(&Bs[oB + i * 16 * BK + fc]);
      }
#pragma unroll
      for (int mt = 0; mt < 2; ++mt)
#pragma unroll
        for (int nt = 0; nt < 2; ++nt)
          acc[mt][nt] = __builtin_amdgcn_mfma_f32_16x16x32_f16(af[mt], bf[nt], acc[mt][nt], 0, 0, 0);
    }
    __syncthreads();
  }

  // epilogue: C/D layout col = lane&15, row = quad*4 + reg   (m89/m91)
  if constexpr (EPI == 0 || EPI == 1 || EPI == 2) {
    const uint2 key = (EPI != 0) ? keys[keyIdx] : make_uint2(0u, 0u);
#pragma unroll
    for (int mt = 0; mt < 2; ++mt)
#pragma unroll
      for (int r = 0; r < 4; ++r) {
        const int gm = m0 + wm + mt * 16 + quad * 4 + r;
#pragma unroll
        for (int nt = 0; nt < 2; ++nt) {
          const int gn = n0 + wn + nt * 16 + l15;
          const float val = acc[mt][nt][r];
          if constexpr (EPI == 0 || EPI == 2)
            outA[(size_t)gm * N + gn] = (f16)val;
          if constexpr (EPI == 1 || EPI == 2) {
            float z   = val + cvec[gn];                 // v_branch == x
            float r01 = rng_u01(key, (uint32_t)(gm * N + gn));
            outH[(size_t)gm * N + gn] = (f16)bern_fast(z, r01);
          }
        }
      }
  } else {
    // EPI 3: a = h@W^T epilogue
    const uint2 key = keys[keyIdx];                     // kV = 3+3s
    float bb[2];
#pragma unroll
    for (int nt = 0; nt < 2; ++nt) bb[nt] = bvec[n0 + wn + nt * 16 + l15];
#pragma unroll
    for (int mt = 0; mt < 2; ++mt)
#pragma unroll
      for (int r = 0; r < 4; ++r) {
        const int gm = m0 + wm + mt * 16 + quad * 4 + r;
        float pa = 0.f, pxa = 0.f, pxb = 0.f;
#pragma unroll
        for (int nt = 0; nt < 2; ++nt) {
          const int gn = n0 + wn + nt * 16 + l15;
          const float aval = acc[mt][nt][r];
          const float xo   = (float)xold[(size_t)gm * N + gn];
          pa  += aval;
          pxa += xo * aval;
          pxb += xo * bb[nt];
          float r01 = rng_u01(key, (uint32_t)(gm * N + gn));
          xnew[(size_t)gm * N + gn] = (f16)bern_fast(aval + bb[nt], r01);
        }
#pragma unroll
        for (int m = 1; m < 16; m <<= 1) {
          pa  += __shfl_xor(pa,  m, 64);
          pxa += __shfl_xor(pxa, m, 64);
          pxb += __shfl_xor(pxb, m, 64);
        }
        if (l15 == 0) {
          const int slot = blockIdx.y * 2 + (wave & 1);
          pA [(size_t)slot * Bn + gm] = pa;
          pXA[(size_t)slot * Bn + gm] = pxa;
          pXB[(size_t)slot * Bn + gm] = pxb;
        }
      }
  }
}

// ---------------------- per-row: partials -> dE -> u_new --------------------
__global__ __launch_bounds__(256) void u_row(
    const float* __restrict__ pA, const float* __restrict__ pXA,
    const float* __restrict__ pXB, const float* __restrict__ bsum,
    const uint2* __restrict__ keys, int kU, float* __restrict__ u)
{
  const int row = blockIdx.x * 256 + threadIdx.x;
  float sa = 0.f, sxa = 0.f, sxb = 0.f;
#pragma unroll
  for (int s = 0; s < 32; ++s) {
    sa  += pA [(size_t)s * Bn + row];
    sxa += pXA[(size_t)s * Bn + row];
    sxb += pXB[(size_t)s * Bn + row];
  }
  const float uo = u[row];
  const float va = (uo > 0.5f) ? sxa : sa - sxa;
  const float vb = (uo > 0.5f) ? sxb : bsum[0] - sxb;
  const float dE = -bsum[0] - sa + 2.f * vb + 2.f * va;
  u[row] = bern_fast(dE, rng_u01(keys[kU], (uint32_t)row));
}

// ------------------------------ free energy --------------------------------
// araw = x@W; actual vW = u? araw : colsum - araw; vb = u? x.b : bsum - x.b
__global__ __launch_bounds__(256) void fe_rows(
    const f16* __restrict__ araw, const f16* __restrict__ x,
    const float* __restrict__ u,
    const float* __restrict__ bvec, const float* __restrict__ cvec,
    const float* __restrict__ colsum, const float* __restrict__ bsum,
    float* __restrict__ Fout)
{
  __shared__ float s1[4], s2[4], s3[4];
  const int row = blockIdx.x;
  const int t = threadIdx.x;
  const float uo = u[row];
  const f16x4  a4 = *(const f16x4*)(araw + (size_t)row * Hn + t * 4);
  const float4 c4 = ((const float4*)cvec)[t];
  const float4 w4 = ((const float4*)colsum)[t];
  const float4 b4 = ((const float4*)bvec)[t];
  const f16x4  x4 = *(const f16x4*)(x + (size_t)row * Vn + t * 4);

  float aa[4] = { (float)a4[0], (float)a4[1], (float)a4[2], (float)a4[3] };
  float cc[4] = { c4.x, c4.y, c4.z, c4.w };
  float ww[4] = { w4.x, w4.y, w4.z, w4.w };
  float bb[4] = { b4.x, b4.y, b4.z, b4.w };
  float S1 = 0.f, S2 = 0.f, xb = 0.f;
#pragma unroll
  for (int j = 0; j < 4; ++j) {
    float m = (uo > 0.5f) ? aa[j] : ww[j] - aa[j];
    S1 += softplus_fast(m + cc[j]);
    S2 += softplus_fast(ww[j] - m + cc[j]);
    xb += (float)x4[j] * bb[j];
  }
#pragma unroll
  for (int off = 32; off > 0; off >>= 1) {
    S1 += __shfl_down(S1, off, 64);
    S2 += __shfl_down(S2, off, 64);
    xb += __shfl_down(xb, off, 64);
  }
  const int wv = t >> 6, ln = t & 63;
  if (ln == 0) { s1[wv] = S1; s2[wv] = S2; s3[wv] = xb; }
  __syncthreads();
  if (t == 0) {
    S1 = s1[0] + s1[1] + s1[2] + s1[3];
    S2 = s2[0] + s2[1] + s2[2] + s2[3];
    xb = s3[0] + s3[1] + s3[2] + s3[3];
    float vb = (uo > 0.5f) ? xb : bsum[0] - xb;
    float negn = vb - S1;
    float negf = (bsum[0] - vb) - S2;
    float mx = fmaxf(negn, negf);
    Fout[row] = -(mx + logf(expf(negn - mx) + expf(negf - mx)));
  }
}

__global__ __launch_bounds__(256) void finalize_k(
    const float* __restrict__ Fd, const float* __restrict__ Fm, float* __restrict__ out)
{
  __shared__ double sb[8];
  double sd = 0.0, sm = 0.0;
  for (int i = threadIdx.x; i < Bn; i += 256) { sd += (double)Fd[i]; sm += (double)Fm[i]; }
  for (int off = 32; off > 0; off >>= 1) { sd += __shfl_down(sd, off, 64); sm += __shfl_down(sm, off, 64); }
  const int wv = threadIdx.x >> 6, ln = threadIdx.x & 63;
  if (ln == 0) { sb[wv] = sd; sb[4 + wv] = sm; }
  __syncthreads();
  if (threadIdx.x == 0) {
    sd = sb[0] + sb[1] + sb[2] + sb[3];
    sm = sb[4] + sb[5] + sb[6] + sb[7];
    out[0] = (float)((sd - sm) / (double)Bn);
  }
}

// ------------------------------ launch glue --------------------------------
extern "C" void kernel_launch(void* const* d_in, const int* in_sizes, int n_in,
                              void* d_out, int out_size, void* d_ws, size_t ws_size,
                              hipStream_t stream) {
  const float* v_data = (const float*)d_in[0];
  const float* W      = (const float*)d_in[1];
  const float* bvec   = (const float*)d_in[2];
  const float* cvec   = (const float*)d_in[3];
  const int*   seedp  = (const int*)d_in[4];
  float* out = (float*)d_out;

  char* ws = (char*)d_ws;
  size_t off = 0;
  auto alloc = [&](size_t bytes) -> void* {
    void* p = ws + off;
    off += (bytes + 255) & ~(size_t)255;
    return p;
  };
  f16*   xb0  = (f16*)alloc((size_t)Bn * Vn * 2);     // 16 MB x ping
  f16*   xb1  = (f16*)alloc((size_t)Bn * Vn * 2);     // 16 MB x pong
  f16*   h    = (f16*)alloc((size_t)Bn * Hn * 2);     // 16 MB
  f16*   araw = (f16*)alloc((size_t)Bn * Hn * 2);     // 16 MB
  f16*   Wf   = (f16*)alloc((size_t)Vn * Hn * 2);     // 2 MB  [V][H]
  f16*   WTf  = (f16*)alloc((size_t)Vn * Hn * 2);     // 2 MB  [H][V]
  float* cpart  = (float*)alloc(64 * Hn * 4);
  float* colsum = (float*)alloc(Hn * 4);
  float* bsum   = (float*)alloc(256);
  uint2* keys   = (uint2*)alloc(64 * sizeof(uint2));
  float* u      = (float*)alloc(Bn * 4);
  float* pA     = (float*)alloc((size_t)32 * Bn * 4); // 1 MB partials
  float* pXA    = (float*)alloc((size_t)32 * Bn * 4);
  float* pXB    = (float*)alloc((size_t)32 * Bn * 4);
  float* Fd     = (float*)alloc(Bn * 4);
  float* Fm     = (float*)alloc(Bn * 4);
  (void)ws_size; (void)in_sizes; (void)n_in; (void)out_size;

  prep_keys<<<1, 64, 0, stream>>>(seedp, keys);
  colsum_part<<<64, 256, 0, stream>>>(W, cpart);
  colsum_red<<<4, 256, 0, stream>>>(cpart, colsum);
  bsum_k<<<1, 256, 0, stream>>>(bvec, bsum);
  cast_W<<<dim3(Hn / 64, Vn / 64), 256, 0, stream>>>(W, Wf, WTf);
  u0_init<<<Bn / 256, 256, 0, stream>>>(keys, u);
  cast_vx<<<(Bn * Vn / 4) / 256, 256, 0, stream>>>(v_data, u, xb0);

  dim3 gg(Bn / 64, Hn / 64);   // 2048 blocks = 8/CU
  f16* xs[2] = { xb0, xb1 };

  // step 0 fused with F(v_data): araw = x0@W (== v_branch@W), h sampled
  gemm_s<2><<<gg, 256, 0, stream>>>(xb0, WTf, araw, h, nullptr, nullptr,
                                    nullptr, cvec, nullptr, nullptr, nullptr, keys, 1);
  fe_rows<<<Bn, 256, 0, stream>>>(araw, xb0, u, bvec, cvec, colsum, bsum, Fd);

  for (int s = 0; s < KSTEPS; ++s) {
    if (s > 0) {
      // h = Bern(sig(x_s@W + c))  [v_branch == x]
      gemm_s<1><<<gg, 256, 0, stream>>>(xs[s & 1], WTf, nullptr, h, nullptr,
                                        nullptr, nullptr, cvec, nullptr, nullptr,
                                        nullptr, keys, 1 + 3 * s);
    }
    // a = h@W^T; fused: x_{s+1} sampled, row-partials emitted
    gemm_s<3><<<gg, 256, 0, stream>>>(h, Wf, nullptr, nullptr, xs[s & 1],
                                      xs[(s + 1) & 1], bvec, nullptr,
                                      pA, pXA, pXB, keys, 3 + 3 * s);
    // dE -> u_{s+1}
    u_row<<<Bn / 256, 256, 0, stream>>>(pA, pXA, pXB, bsum, keys, 2 + 3 * s, u);
  }

  // F(v_model): araw = x10@W; fe branches with u10
  gemm_s<0><<<gg, 256, 0, stream>>>(xs[KSTEPS & 1], WTf, araw, nullptr, nullptr,
                                    nullptr, nullptr, nullptr, nullptr, nullptr,
                                    nullptr, keys, 0);
  fe_rows<<<Bn, 256, 0, stream>>>(araw, xs[KSTEPS & 1], u, bvec, cvec, colsum, bsum, Fm);

  finalize_k<<<1, 256, 0, stream>>>(Fd, Fm, out);
}

// Round 15
// 1028.971 us; speedup vs baseline: 1.0778x; 1.0778x over previous
//
#include <hip/hip_runtime.h>
#include <hip/hip_bf16.h>
#include <stdint.h>
#include <math.h>

// ---------------------------------------------------------------------------
// SymmetricRBM: CD loss, 10-step Gibbs, JAX-threefry-exact RNG.
// B=8192, V=H=1024. R14->R15: DEFER the u-recurrence.
// R14's 10 u_row launches were latency-bound (~12 us each, 32 blocks).
// After the unflipped-x rewrite NOTHING in the loop consumes u, so partials
// go to per-step slabs [10][32][Bn] and ONE u_chain kernel walks the 10-step
// recurrence per row in registers (same slot order, same keys -> bit-exact).
// gemm core frozen (R12: 64x64xBK64, 8 blocks/CU, 0 conflicts).
// ---------------------------------------------------------------------------

static constexpr int Bn = 8192;
static constexpr int Vn = 1024;
static constexpr int Hn = 1024;
static constexpr int KSTEPS = 10;

typedef _Float16 f16;
typedef f16   f16x4 __attribute__((ext_vector_type(4)));
typedef f16   f16x8 __attribute__((ext_vector_type(8)));
typedef float f32x4 __attribute__((ext_vector_type(4)));

#define GLOBAL_LOAD_LDS16(g, l)                                              \
  __builtin_amdgcn_global_load_lds(                                          \
      (const __attribute__((address_space(1))) uint32_t*)(g),                \
      (__attribute__((address_space(3))) uint32_t*)(l), 16, 0, 0)

// ------------------------- Threefry-2x32 (JAX-exact) -----------------------
__device__ __forceinline__ uint32_t rotl32(uint32_t x, int d) {
  return (x << d) | (x >> (32 - d));
}

__device__ __forceinline__ void tf2x32(uint32_t k0, uint32_t k1,
                                       uint32_t x0, uint32_t x1,
                                       uint32_t& o0, uint32_t& o1) {
  uint32_t k2 = k0 ^ k1 ^ 0x1BD11BDAu;
#define TFR(r) { x0 += x1; x1 = rotl32(x1, (r)); x1 ^= x0; }
  x0 += k0; x1 += k1;
  TFR(13) TFR(15) TFR(26) TFR(6)
  x0 += k1; x1 += k2 + 1u;
  TFR(17) TFR(29) TFR(16) TFR(24)
  x0 += k2; x1 += k0 + 2u;
  TFR(13) TFR(15) TFR(26) TFR(6)
  x0 += k0; x1 += k1 + 3u;
  TFR(17) TFR(29) TFR(16) TFR(24)
  x0 += k1; x1 += k2 + 4u;
  TFR(13) TFR(15) TFR(26) TFR(6)
  x0 += k2; x1 += k0 + 5u;
#undef TFR
  o0 = x0; o1 = x1;
}

__device__ __forceinline__ float rng_u01(uint2 key, uint32_t idx) {
  uint32_t o0, o1;
  tf2x32(key.x, key.y, 0u, idx, o0, o1);
  uint32_t bits = o0 ^ o1;
  return __uint_as_float((bits >> 9) | 0x3F800000u) - 1.0f;
}

// fast Bernoulli accept: r01 < sigmoid(z)  <=>  r01*(1+exp(-z)) < 1
__device__ __forceinline__ float bern_fast(float z, float r01) {
  float e = __expf(-z);
  return (__builtin_fmaf(r01, e, r01) < 1.0f) ? 1.f : 0.f;
}
__device__ __forceinline__ float softplus_fast(float x) {
  return fmaxf(x, 0.f) + __logf(1.f + __expf(-fabsf(x)));
}

// ------------------------------- prep kernels ------------------------------
__global__ void prep_keys(const int* __restrict__ seedp, uint2* __restrict__ keys) {
  if (threadIdx.x != 0 || blockIdx.x != 0) return;
  uint32_t seed = (uint32_t)(*seedp);
  uint2 key = make_uint2(0u, seed);
  uint2 nk, kk;
  tf2x32(key.x, key.y, 0u, 0u, nk.x, nk.y);
  tf2x32(key.x, key.y, 0u, 1u, kk.x, kk.y);
  keys[0] = kk;   // k0
  key = nk;
  for (int s = 0; s < KSTEPS; ++s) {
    uint2 t0, t1, t2, t3;
    tf2x32(key.x, key.y, 0u, 0u, t0.x, t0.y);
    tf2x32(key.x, key.y, 0u, 1u, t1.x, t1.y);
    tf2x32(key.x, key.y, 0u, 2u, t2.x, t2.y);
    tf2x32(key.x, key.y, 0u, 3u, t3.x, t3.y);
    key = t0;
    keys[1 + 3*s] = t1;  // k1
    keys[2 + 3*s] = t2;  // k2
    keys[3 + 3*s] = t3;  // k3
  }
}

__global__ __launch_bounds__(256) void colsum_part(
    const float* __restrict__ W, float* __restrict__ part) {
  const int bx = blockIdx.x, t = threadIdx.x;
  float s0 = 0.f, s1 = 0.f, s2 = 0.f, s3 = 0.f;
#pragma unroll
  for (int r = 0; r < 16; ++r) {
    const float* row = W + (size_t)(bx * 16 + r) * Hn;
    s0 += row[t]; s1 += row[t + 256]; s2 += row[t + 512]; s3 += row[t + 768];
  }
  float* p = part + (size_t)bx * Hn;
  p[t] = s0; p[t + 256] = s1; p[t + 512] = s2; p[t + 768] = s3;
}

__global__ __launch_bounds__(256) void colsum_red(
    const float* __restrict__ part, float* __restrict__ cs) {
  const int col = blockIdx.x * 256 + threadIdx.x;
  float s = 0.f;
#pragma unroll
  for (int k = 0; k < 64; ++k) s += part[(size_t)k * Hn + col];
  cs[col] = s;
}

__global__ void bsum_k(const float* __restrict__ bvec, float* __restrict__ bs) {
  __shared__ float sb[4];
  float s = 0.f;
  for (int i = threadIdx.x; i < Vn; i += 256) s += bvec[i];
  for (int off = 32; off > 0; off >>= 1) s += __shfl_down(s, off, 64);
  int wv = threadIdx.x >> 6, ln = threadIdx.x & 63;
  if (ln == 0) sb[wv] = s;
  __syncthreads();
  if (threadIdx.x == 0) bs[0] = sb[0] + sb[1] + sb[2] + sb[3];
}

__global__ __launch_bounds__(256) void cast_W(
    const float* __restrict__ W, f16* __restrict__ Wf, f16* __restrict__ WTf) {
  __shared__ f16 tile[64][65];
  const int j0 = blockIdx.x * 64, i0 = blockIdx.y * 64;
  const int tx = threadIdx.x & 63, tg = threadIdx.x >> 6;
#pragma unroll 4
  for (int rr = 0; rr < 16; ++rr) {
    const int row = tg * 16 + rr;
    float w = W[(size_t)(i0 + row) * Hn + j0 + tx];
    f16 hw = (f16)w;
    Wf[(size_t)(i0 + row) * Hn + j0 + tx] = hw;
    tile[row][tx] = hw;
  }
  __syncthreads();
#pragma unroll 4
  for (int rr = 0; rr < 16; ++rr) {
    const int row = tg * 16 + rr;
    WTf[(size_t)(j0 + row) * Vn + i0 + tx] = tile[tx][row];
  }
}

__global__ void u0_init(const uint2* __restrict__ keys, float* __restrict__ u) {
  int b = blockIdx.x * 256 + threadIdx.x;
  float r01 = rng_u01(keys[0], (uint32_t)b);
  u[b] = (r01 < 0.5f) ? 1.f : 0.f;
}

// x0 = u0 ? v_data : 1 - v_data   (unflipped carry; v = u?x:1-x)
__global__ __launch_bounds__(256) void cast_vx(
    const float* __restrict__ vd, const float* __restrict__ u,
    f16* __restrict__ x) {
  const int idx = blockIdx.x * 256 + threadIdx.x;   // group of 4
  const int row = idx >> 8;
  const float uo = u[row];
  const float4 d = ((const float4*)vd)[idx];
  f16x4 o;
  if (uo > 0.5f) { o[0]=(f16)d.x; o[1]=(f16)d.y; o[2]=(f16)d.z; o[3]=(f16)d.w; }
  else { o[0]=(f16)(1.f-d.x); o[1]=(f16)(1.f-d.y); o[2]=(f16)(1.f-d.z); o[3]=(f16)(1.f-d.w); }
  *(f16x4*)(x + (size_t)idx * 4) = o;
}

// ------------------------- GEMM: 64x64 max-occupancy ------------------------
// Core frozen from R12.  EPI 0: store C.  EPI 1: h=Bern(sig(C+c)).
// EPI 2: store C AND h.  EPI 3: x_new=Bern(sig(C+b)) + row-partials into the
// given (per-step) slab [32][Bn].
template <int EPI>
__global__ __launch_bounds__(256, 8) void gemm_s(
    const f16* __restrict__ A, const f16* __restrict__ Bm,
    f16* __restrict__ outA, f16* __restrict__ outH,
    const f16* __restrict__ xold, f16* __restrict__ xnew,
    const float* __restrict__ bvec, const float* __restrict__ cvec,
    float* __restrict__ pA, float* __restrict__ pXA, float* __restrict__ pXB,
    const uint2* __restrict__ keys, int keyIdx)
{
  constexpr int N = 1024, K = 1024, BK = 64;
  __shared__ alignas(16) f16 As[64 * BK];   // 8 KB
  __shared__ alignas(16) f16 Bs[64 * BK];   // 8 KB

  const int t = threadIdx.x, wave = t >> 6, lane = t & 63;
  const int l15 = lane & 15, quad = lane >> 4;
  const int m0 = blockIdx.x * 64, n0 = blockIdx.y * 64;
  const int wm = (wave >> 1) * 32, wn = (wave & 1) * 32;

  const int rbase = lane >> 3;
  const int gch   = (lane & 7) ^ rbase;
  const f16* gA = A  + (size_t)(m0 + wave * 16 + rbase) * K + gch * 8;
  const f16* gB = Bm + (size_t)(n0 + wave * 16 + rbase) * K + gch * 8;
  f16* lA = As + wave * 16 * BK;
  f16* lB = Bs + wave * 16 * BK;

  const int swz = l15 & 7;
  const int oA  = (wm + l15) * BK;
  const int oB  = (wn + l15) * BK;

  f32x4 acc[2][2] = {};

  for (int k0 = 0; k0 < K; k0 += BK) {
    GLOBAL_LOAD_LDS16(gA + k0,         lA);
    GLOBAL_LOAD_LDS16(gA + k0 + 8 * K, lA + 8 * BK);
    GLOBAL_LOAD_LDS16(gB + k0,         lB);
    GLOBAL_LOAD_LDS16(gB + k0 + 8 * K, lB + 8 * BK);
    __syncthreads();

#pragma unroll
    for (int kc = 0; kc < 2; ++kc) {
      const int fc = ((kc * 4 + quad) ^ swz) * 8;
      f16x8 af[2], bf[2];
#pragma unroll
      for (int i = 0; i < 2; ++i) {
        af[i] = *(const f16x8*)(&As[oA + i * 16 * BK + fc]);
        bf[i] = *(const f16x8*)(&Bs[oB + i * 16 * BK + fc]);
      }
#pragma unroll
      for (int mt = 0; mt < 2; ++mt)
#pragma unroll
        for (int nt = 0; nt < 2; ++nt)
          acc[mt][nt] = __builtin_amdgcn_mfma_f32_16x16x32_f16(af[mt], bf[nt], acc[mt][nt], 0, 0, 0);
    }
    __syncthreads();
  }

  // epilogue: C/D layout col = lane&15, row = quad*4 + reg   (m89/m91)
  if constexpr (EPI == 0 || EPI == 1 || EPI == 2) {
    const uint2 key = (EPI != 0) ? keys[keyIdx] : make_uint2(0u, 0u);
#pragma unroll
    for (int mt = 0; mt < 2; ++mt)
#pragma unroll
      for (int r = 0; r < 4; ++r) {
        const int gm = m0 + wm + mt * 16 + quad * 4 + r;
#pragma unroll
        for (int nt = 0; nt < 2; ++nt) {
          const int gn = n0 + wn + nt * 16 + l15;
          const float val = acc[mt][nt][r];
          if constexpr (EPI == 0 || EPI == 2)
            outA[(size_t)gm * N + gn] = (f16)val;
          if constexpr (EPI == 1 || EPI == 2) {
            float z   = val + cvec[gn];                 // v_branch == x
            float r01 = rng_u01(key, (uint32_t)(gm * N + gn));
            outH[(size_t)gm * N + gn] = (f16)bern_fast(z, r01);
          }
        }
      }
  } else {
    // EPI 3: a = h@W^T epilogue, partials into per-step slab
    const uint2 key = keys[keyIdx];                     // kV = 3+3s
    float bb[2];
#pragma unroll
    for (int nt = 0; nt < 2; ++nt) bb[nt] = bvec[n0 + wn + nt * 16 + l15];
#pragma unroll
    for (int mt = 0; mt < 2; ++mt)
#pragma unroll
      for (int r = 0; r < 4; ++r) {
        const int gm = m0 + wm + mt * 16 + quad * 4 + r;
        float pa = 0.f, pxa = 0.f, pxb = 0.f;
#pragma unroll
        for (int nt = 0; nt < 2; ++nt) {
          const int gn = n0 + wn + nt * 16 + l15;
          const float aval = acc[mt][nt][r];
          const float xo   = (float)xold[(size_t)gm * N + gn];
          pa  += aval;
          pxa += xo * aval;
          pxb += xo * bb[nt];
          float r01 = rng_u01(key, (uint32_t)(gm * N + gn));
          xnew[(size_t)gm * N + gn] = (f16)bern_fast(aval + bb[nt], r01);
        }
#pragma unroll
        for (int m = 1; m < 16; m <<= 1) {
          pa  += __shfl_xor(pa,  m, 64);
          pxa += __shfl_xor(pxa, m, 64);
          pxb += __shfl_xor(pxb, m, 64);
        }
        if (l15 == 0) {
          const int slot = blockIdx.y * 2 + (wave & 1);
          pA [(size_t)slot * Bn + gm] = pa;
          pXA[(size_t)slot * Bn + gm] = pxa;
          pXB[(size_t)slot * Bn + gm] = pxb;
        }
      }
  }
}

// ------------- deferred u-recurrence: one launch for all 10 steps -----------
__global__ __launch_bounds__(256) void u_chain(
    const float* __restrict__ pA, const float* __restrict__ pXA,
    const float* __restrict__ pXB, const float* __restrict__ bsum,
    const uint2* __restrict__ keys, float* __restrict__ u)
{
  const int row = blockIdx.x * 256 + threadIdx.x;
  const float bs = bsum[0];
  float uo = u[row];                      // u0
  for (int s = 0; s < KSTEPS; ++s) {
    const size_t so = (size_t)s * 32 * Bn;
    float sa = 0.f, sxa = 0.f, sxb = 0.f;
#pragma unroll
    for (int k = 0; k < 32; ++k) {
      sa  += pA [so + (size_t)k * Bn + row];
      sxa += pXA[so + (size_t)k * Bn + row];
      sxb += pXB[so + (size_t)k * Bn + row];
    }
    const float va = (uo > 0.5f) ? sxa : sa - sxa;
    const float vb = (uo > 0.5f) ? sxb : bs - sxb;
    const float dE = -bs - sa + 2.f * vb + 2.f * va;
    uo = bern_fast(dE, rng_u01(keys[2 + 3 * s], (uint32_t)row));
  }
  u[row] = uo;
}

// ------------------------------ free energy --------------------------------
__global__ __launch_bounds__(256) void fe_rows(
    const f16* __restrict__ araw, const f16* __restrict__ x,
    const float* __restrict__ u,
    const float* __restrict__ bvec, const float* __restrict__ cvec,
    const float* __restrict__ colsum, const float* __restrict__ bsum,
    float* __restrict__ Fout)
{
  __shared__ float s1[4], s2[4], s3[4];
  const int row = blockIdx.x;
  const int t = threadIdx.x;
  const float uo = u[row];
  const f16x4  a4 = *(const f16x4*)(araw + (size_t)row * Hn + t * 4);
  const float4 c4 = ((const float4*)cvec)[t];
  const float4 w4 = ((const float4*)colsum)[t];
  const float4 b4 = ((const float4*)bvec)[t];
  const f16x4  x4 = *(const f16x4*)(x + (size_t)row * Vn + t * 4);

  float aa[4] = { (float)a4[0], (float)a4[1], (float)a4[2], (float)a4[3] };
  float cc[4] = { c4.x, c4.y, c4.z, c4.w };
  float ww[4] = { w4.x, w4.y, w4.z, w4.w };
  float bb[4] = { b4.x, b4.y, b4.z, b4.w };
  float S1 = 0.f, S2 = 0.f, xb = 0.f;
#pragma unroll
  for (int j = 0; j < 4; ++j) {
    float m = (uo > 0.5f) ? aa[j] : ww[j] - aa[j];
    S1 += softplus_fast(m + cc[j]);
    S2 += softplus_fast(ww[j] - m + cc[j]);
    xb += (float)x4[j] * bb[j];
  }
#pragma unroll
  for (int off = 32; off > 0; off >>= 1) {
    S1 += __shfl_down(S1, off, 64);
    S2 += __shfl_down(S2, off, 64);
    xb += __shfl_down(xb, off, 64);
  }
  const int wv = t >> 6, ln = t & 63;
  if (ln == 0) { s1[wv] = S1; s2[wv] = S2; s3[wv] = xb; }
  __syncthreads();
  if (t == 0) {
    S1 = s1[0] + s1[1] + s1[2] + s1[3];
    S2 = s2[0] + s2[1] + s2[2] + s2[3];
    xb = s3[0] + s3[1] + s3[2] + s3[3];
    float vb = (uo > 0.5f) ? xb : bsum[0] - xb;
    float negn = vb - S1;
    float negf = (bsum[0] - vb) - S2;
    float mx = fmaxf(negn, negf);
    Fout[row] = -(mx + logf(expf(negn - mx) + expf(negf - mx)));
  }
}

__global__ __launch_bounds__(256) void finalize_k(
    const float* __restrict__ Fd, const float* __restrict__ Fm, float* __restrict__ out)
{
  __shared__ double sb[8];
  double sd = 0.0, sm = 0.0;
  for (int i = threadIdx.x; i < Bn; i += 256) { sd += (double)Fd[i]; sm += (double)Fm[i]; }
  for (int off = 32; off > 0; off >>= 1) { sd += __shfl_down(sd, off, 64); sm += __shfl_down(sm, off, 64); }
  const int wv = threadIdx.x >> 6, ln = threadIdx.x & 63;
  if (ln == 0) { sb[wv] = sd; sb[4 + wv] = sm; }
  __syncthreads();
  if (threadIdx.x == 0) {
    sd = sb[0] + sb[1] + sb[2] + sb[3];
    sm = sb[4] + sb[5] + sb[6] + sb[7];
    out[0] = (float)((sd - sm) / (double)Bn);
  }
}

// ------------------------------ launch glue --------------------------------
extern "C" void kernel_launch(void* const* d_in, const int* in_sizes, int n_in,
                              void* d_out, int out_size, void* d_ws, size_t ws_size,
                              hipStream_t stream) {
  const float* v_data = (const float*)d_in[0];
  const float* W      = (const float*)d_in[1];
  const float* bvec   = (const float*)d_in[2];
  const float* cvec   = (const float*)d_in[3];
  const int*   seedp  = (const int*)d_in[4];
  float* out = (float*)d_out;

  char* ws = (char*)d_ws;
  size_t off = 0;
  auto alloc = [&](size_t bytes) -> void* {
    void* p = ws + off;
    off += (bytes + 255) & ~(size_t)255;
    return p;
  };
  f16*   xb0  = (f16*)alloc((size_t)Bn * Vn * 2);     // 16 MB x ping
  f16*   xb1  = (f16*)alloc((size_t)Bn * Vn * 2);     // 16 MB x pong
  f16*   h    = (f16*)alloc((size_t)Bn * Hn * 2);     // 16 MB
  f16*   araw = (f16*)alloc((size_t)Bn * Hn * 2);     // 16 MB
  f16*   Wf   = (f16*)alloc((size_t)Vn * Hn * 2);     // 2 MB  [V][H]
  f16*   WTf  = (f16*)alloc((size_t)Vn * Hn * 2);     // 2 MB  [H][V]
  float* cpart  = (float*)alloc(64 * Hn * 4);
  float* colsum = (float*)alloc(Hn * 4);
  float* bsum   = (float*)alloc(256);
  uint2* keys   = (uint2*)alloc(64 * sizeof(uint2));
  float* u      = (float*)alloc(Bn * 4);
  float* pA     = (float*)alloc((size_t)KSTEPS * 32 * Bn * 4); // 10.5 MB
  float* pXA    = (float*)alloc((size_t)KSTEPS * 32 * Bn * 4);
  float* pXB    = (float*)alloc((size_t)KSTEPS * 32 * Bn * 4);
  float* Fd     = (float*)alloc(Bn * 4);
  float* Fm     = (float*)alloc(Bn * 4);
  (void)ws_size; (void)in_sizes; (void)n_in; (void)out_size;

  prep_keys<<<1, 64, 0, stream>>>(seedp, keys);
  colsum_part<<<64, 256, 0, stream>>>(W, cpart);
  colsum_red<<<4, 256, 0, stream>>>(cpart, colsum);
  bsum_k<<<1, 256, 0, stream>>>(bvec, bsum);
  cast_W<<<dim3(Hn / 64, Vn / 64), 256, 0, stream>>>(W, Wf, WTf);
  u0_init<<<Bn / 256, 256, 0, stream>>>(keys, u);
  cast_vx<<<(Bn * Vn / 4) / 256, 256, 0, stream>>>(v_data, u, xb0);

  dim3 gg(Bn / 64, Hn / 64);   // 2048 blocks = 8/CU
  f16* xs[2] = { xb0, xb1 };

  // step 0 fused with F(v_data): araw = x0@W (== v_branch@W), h sampled
  gemm_s<2><<<gg, 256, 0, stream>>>(xb0, WTf, araw, h, nullptr, nullptr,
                                    nullptr, cvec, nullptr, nullptr, nullptr, keys, 1);
  fe_rows<<<Bn, 256, 0, stream>>>(araw, xb0, u, bvec, cvec, colsum, bsum, Fd);

  for (int s = 0; s < KSTEPS; ++s) {
    if (s > 0) {
      gemm_s<1><<<gg, 256, 0, stream>>>(xs[s & 1], WTf, nullptr, h, nullptr,
                                        nullptr, nullptr, cvec, nullptr, nullptr,
                                        nullptr, keys, 1 + 3 * s);
    }
    const size_t so = (size_t)s * 32 * Bn;
    gemm_s<3><<<gg, 256, 0, stream>>>(h, Wf, nullptr, nullptr, xs[s & 1],
                                      xs[(s + 1) & 1], bvec, nullptr,
                                      pA + so, pXA + so, pXB + so, keys, 3 + 3 * s);
  }

  // F(v_model) gemm (u-independent), then the whole u-chain in one launch
  gemm_s<0><<<gg, 256, 0, stream>>>(xs[KSTEPS & 1], WTf, araw, nullptr, nullptr,
                                    nullptr, nullptr, nullptr, nullptr, nullptr,
                                    nullptr, keys, 0);
  u_chain<<<Bn / 256, 256, 0, stream>>>(pA, pXA, pXB, bsum, keys, u);
  fe_rows<<<Bn, 256, 0, stream>>>(araw, xs[KSTEPS & 1], u, bvec, cvec, colsum, bsum, Fm);

  finalize_k<<<1, 256, 0, stream>>>(Fd, Fm, out);
}

// Round 16
// 947.221 us; speedup vs baseline: 1.1708x; 1.0863x over previous
//
#include <hip/hip_runtime.h>
#include <hip/hip_bf16.h>
#include <stdint.h>
#include <math.h>

// ---------------------------------------------------------------------------
// SymmetricRBM: CD loss, 10-step Gibbs, JAX-threefry-exact RNG.
// B=8192, V=H=1024. R15->R16: u_chain was 96 us (32 blocks, 1.3% occupancy,
// one THREAD per row doing 960 strided loads). Now: partial slabs stored
// slot-major [step][row][32]; u_chain v2 gives each row a 32-lane half-wave
// (coalesced 256B reads + butterfly shuffle reduce) -> ~10 us.
// gemm core frozen (R12: 64x64xBK64, 8 blocks/CU, 0 conflicts, ~44 us).
// ---------------------------------------------------------------------------

static constexpr int Bn = 8192;
static constexpr int Vn = 1024;
static constexpr int Hn = 1024;
static constexpr int KSTEPS = 10;

typedef _Float16 f16;
typedef f16   f16x4 __attribute__((ext_vector_type(4)));
typedef f16   f16x8 __attribute__((ext_vector_type(8)));
typedef float f32x4 __attribute__((ext_vector_type(4)));

#define GLOBAL_LOAD_LDS16(g, l)                                              \
  __builtin_amdgcn_global_load_lds(                                          \
      (const __attribute__((address_space(1))) uint32_t*)(g),                \
      (__attribute__((address_space(3))) uint32_t*)(l), 16, 0, 0)

// ------------------------- Threefry-2x32 (JAX-exact) -----------------------
__device__ __forceinline__ uint32_t rotl32(uint32_t x, int d) {
  return (x << d) | (x >> (32 - d));
}

__device__ __forceinline__ void tf2x32(uint32_t k0, uint32_t k1,
                                       uint32_t x0, uint32_t x1,
                                       uint32_t& o0, uint32_t& o1) {
  uint32_t k2 = k0 ^ k1 ^ 0x1BD11BDAu;
#define TFR(r) { x0 += x1; x1 = rotl32(x1, (r)); x1 ^= x0; }
  x0 += k0; x1 += k1;
  TFR(13) TFR(15) TFR(26) TFR(6)
  x0 += k1; x1 += k2 + 1u;
  TFR(17) TFR(29) TFR(16) TFR(24)
  x0 += k2; x1 += k0 + 2u;
  TFR(13) TFR(15) TFR(26) TFR(6)
  x0 += k0; x1 += k1 + 3u;
  TFR(17) TFR(29) TFR(16) TFR(24)
  x0 += k1; x1 += k2 + 4u;
  TFR(13) TFR(15) TFR(26) TFR(6)
  x0 += k2; x1 += k0 + 5u;
#undef TFR
  o0 = x0; o1 = x1;
}

__device__ __forceinline__ float rng_u01(uint2 key, uint32_t idx) {
  uint32_t o0, o1;
  tf2x32(key.x, key.y, 0u, idx, o0, o1);
  uint32_t bits = o0 ^ o1;
  return __uint_as_float((bits >> 9) | 0x3F800000u) - 1.0f;
}

// fast Bernoulli accept: r01 < sigmoid(z)  <=>  r01*(1+exp(-z)) < 1
__device__ __forceinline__ float bern_fast(float z, float r01) {
  float e = __expf(-z);
  return (__builtin_fmaf(r01, e, r01) < 1.0f) ? 1.f : 0.f;
}
__device__ __forceinline__ float softplus_fast(float x) {
  return fmaxf(x, 0.f) + __logf(1.f + __expf(-fabsf(x)));
}

// ------------------------------- prep kernels ------------------------------
__global__ void prep_keys(const int* __restrict__ seedp, uint2* __restrict__ keys) {
  if (threadIdx.x != 0 || blockIdx.x != 0) return;
  uint32_t seed = (uint32_t)(*seedp);
  uint2 key = make_uint2(0u, seed);
  uint2 nk, kk;
  tf2x32(key.x, key.y, 0u, 0u, nk.x, nk.y);
  tf2x32(key.x, key.y, 0u, 1u, kk.x, kk.y);
  keys[0] = kk;   // k0
  key = nk;
  for (int s = 0; s < KSTEPS; ++s) {
    uint2 t0, t1, t2, t3;
    tf2x32(key.x, key.y, 0u, 0u, t0.x, t0.y);
    tf2x32(key.x, key.y, 0u, 1u, t1.x, t1.y);
    tf2x32(key.x, key.y, 0u, 2u, t2.x, t2.y);
    tf2x32(key.x, key.y, 0u, 3u, t3.x, t3.y);
    key = t0;
    keys[1 + 3*s] = t1;  // k1
    keys[2 + 3*s] = t2;  // k2
    keys[3 + 3*s] = t3;  // k3
  }
}

__global__ __launch_bounds__(256) void colsum_part(
    const float* __restrict__ W, float* __restrict__ part) {
  const int bx = blockIdx.x, t = threadIdx.x;
  float s0 = 0.f, s1 = 0.f, s2 = 0.f, s3 = 0.f;
#pragma unroll
  for (int r = 0; r < 16; ++r) {
    const float* row = W + (size_t)(bx * 16 + r) * Hn;
    s0 += row[t]; s1 += row[t + 256]; s2 += row[t + 512]; s3 += row[t + 768];
  }
  float* p = part + (size_t)bx * Hn;
  p[t] = s0; p[t + 256] = s1; p[t + 512] = s2; p[t + 768] = s3;
}

__global__ __launch_bounds__(256) void colsum_red(
    const float* __restrict__ part, float* __restrict__ cs) {
  const int col = blockIdx.x * 256 + threadIdx.x;
  float s = 0.f;
#pragma unroll
  for (int k = 0; k < 64; ++k) s += part[(size_t)k * Hn + col];
  cs[col] = s;
}

__global__ void bsum_k(const float* __restrict__ bvec, float* __restrict__ bs) {
  __shared__ float sb[4];
  float s = 0.f;
  for (int i = threadIdx.x; i < Vn; i += 256) s += bvec[i];
  for (int off = 32; off > 0; off >>= 1) s += __shfl_down(s, off, 64);
  int wv = threadIdx.x >> 6, ln = threadIdx.x & 63;
  if (ln == 0) sb[wv] = s;
  __syncthreads();
  if (threadIdx.x == 0) bs[0] = sb[0] + sb[1] + sb[2] + sb[3];
}

__global__ __launch_bounds__(256) void cast_W(
    const float* __restrict__ W, f16* __restrict__ Wf, f16* __restrict__ WTf) {
  __shared__ f16 tile[64][65];
  const int j0 = blockIdx.x * 64, i0 = blockIdx.y * 64;
  const int tx = threadIdx.x & 63, tg = threadIdx.x >> 6;
#pragma unroll 4
  for (int rr = 0; rr < 16; ++rr) {
    const int row = tg * 16 + rr;
    float w = W[(size_t)(i0 + row) * Hn + j0 + tx];
    f16 hw = (f16)w;
    Wf[(size_t)(i0 + row) * Hn + j0 + tx] = hw;
    tile[row][tx] = hw;
  }
  __syncthreads();
#pragma unroll 4
  for (int rr = 0; rr < 16; ++rr) {
    const int row = tg * 16 + rr;
    WTf[(size_t)(j0 + row) * Vn + i0 + tx] = tile[tx][row];
  }
}

__global__ void u0_init(const uint2* __restrict__ keys, float* __restrict__ u) {
  int b = blockIdx.x * 256 + threadIdx.x;
  float r01 = rng_u01(keys[0], (uint32_t)b);
  u[b] = (r01 < 0.5f) ? 1.f : 0.f;
}

// x0 = u0 ? v_data : 1 - v_data   (unflipped carry; v = u?x:1-x)
__global__ __launch_bounds__(256) void cast_vx(
    const float* __restrict__ vd, const float* __restrict__ u,
    f16* __restrict__ x) {
  const int idx = blockIdx.x * 256 + threadIdx.x;   // group of 4
  const int row = idx >> 8;
  const float uo = u[row];
  const float4 d = ((const float4*)vd)[idx];
  f16x4 o;
  if (uo > 0.5f) { o[0]=(f16)d.x; o[1]=(f16)d.y; o[2]=(f16)d.z; o[3]=(f16)d.w; }
  else { o[0]=(f16)(1.f-d.x); o[1]=(f16)(1.f-d.y); o[2]=(f16)(1.f-d.z); o[3]=(f16)(1.f-d.w); }
  *(f16x4*)(x + (size_t)idx * 4) = o;
}

// ------------------------- GEMM: 64x64 max-occupancy ------------------------
// Core frozen from R12.  EPI 0: store C.  EPI 1: h=Bern(sig(C+c)).
// EPI 2: store C AND h.  EPI 3: x_new=Bern(sig(C+b)) + row-partials into the
// per-step slab, slot-major [row][32] (slot = blockIdx.y*2 + (wave&1)).
template <int EPI>
__global__ __launch_bounds__(256, 8) void gemm_s(
    const f16* __restrict__ A, const f16* __restrict__ Bm,
    f16* __restrict__ outA, f16* __restrict__ outH,
    const f16* __restrict__ xold, f16* __restrict__ xnew,
    const float* __restrict__ bvec, const float* __restrict__ cvec,
    float* __restrict__ pA, float* __restrict__ pXA, float* __restrict__ pXB,
    const uint2* __restrict__ keys, int keyIdx)
{
  constexpr int N = 1024, K = 1024, BK = 64;
  __shared__ alignas(16) f16 As[64 * BK];   // 8 KB
  __shared__ alignas(16) f16 Bs[64 * BK];   // 8 KB

  const int t = threadIdx.x, wave = t >> 6, lane = t & 63;
  const int l15 = lane & 15, quad = lane >> 4;
  const int m0 = blockIdx.x * 64, n0 = blockIdx.y * 64;
  const int wm = (wave >> 1) * 32, wn = (wave & 1) * 32;

  const int rbase = lane >> 3;
  const int gch   = (lane & 7) ^ rbase;
  const f16* gA = A  + (size_t)(m0 + wave * 16 + rbase) * K + gch * 8;
  const f16* gB = Bm + (size_t)(n0 + wave * 16 + rbase) * K + gch * 8;
  f16* lA = As + wave * 16 * BK;
  f16* lB = Bs + wave * 16 * BK;

  const int swz = l15 & 7;
  const int oA  = (wm + l15) * BK;
  const int oB  = (wn + l15) * BK;

  f32x4 acc[2][2] = {};

  for (int k0 = 0; k0 < K; k0 += BK) {
    GLOBAL_LOAD_LDS16(gA + k0,         lA);
    GLOBAL_LOAD_LDS16(gA + k0 + 8 * K, lA + 8 * BK);
    GLOBAL_LOAD_LDS16(gB + k0,         lB);
    GLOBAL_LOAD_LDS16(gB + k0 + 8 * K, lB + 8 * BK);
    __syncthreads();

#pragma unroll
    for (int kc = 0; kc < 2; ++kc) {
      const int fc = ((kc * 4 + quad) ^ swz) * 8;
      f16x8 af[2], bf[2];
#pragma unroll
      for (int i = 0; i < 2; ++i) {
        af[i] = *(const f16x8*)(&As[oA + i * 16 * BK + fc]);
        bf[i] = *(const f16x8*)(&Bs[oB + i * 16 * BK + fc]);
      }
#pragma unroll
      for (int mt = 0; mt < 2; ++mt)
#pragma unroll
        for (int nt = 0; nt < 2; ++nt)
          acc[mt][nt] = __builtin_amdgcn_mfma_f32_16x16x32_f16(af[mt], bf[nt], acc[mt][nt], 0, 0, 0);
    }
    __syncthreads();
  }

  // epilogue: C/D layout col = lane&15, row = quad*4 + reg   (m89/m91)
  if constexpr (EPI == 0 || EPI == 1 || EPI == 2) {
    const uint2 key = (EPI != 0) ? keys[keyIdx] : make_uint2(0u, 0u);
#pragma unroll
    for (int mt = 0; mt < 2; ++mt)
#pragma unroll
      for (int r = 0; r < 4; ++r) {
        const int gm = m0 + wm + mt * 16 + quad * 4 + r;
#pragma unroll
        for (int nt = 0; nt < 2; ++nt) {
          const int gn = n0 + wn + nt * 16 + l15;
          const float val = acc[mt][nt][r];
          if constexpr (EPI == 0 || EPI == 2)
            outA[(size_t)gm * N + gn] = (f16)val;
          if constexpr (EPI == 1 || EPI == 2) {
            float z   = val + cvec[gn];                 // v_branch == x
            float r01 = rng_u01(key, (uint32_t)(gm * N + gn));
            outH[(size_t)gm * N + gn] = (f16)bern_fast(z, r01);
          }
        }
      }
  } else {
    // EPI 3: a = h@W^T epilogue, partials slot-major [row][32]
    const uint2 key = keys[keyIdx];                     // kV = 3+3s
    float bb[2];
#pragma unroll
    for (int nt = 0; nt < 2; ++nt) bb[nt] = bvec[n0 + wn + nt * 16 + l15];
#pragma unroll
    for (int mt = 0; mt < 2; ++mt)
#pragma unroll
      for (int r = 0; r < 4; ++r) {
        const int gm = m0 + wm + mt * 16 + quad * 4 + r;
        float pa = 0.f, pxa = 0.f, pxb = 0.f;
#pragma unroll
        for (int nt = 0; nt < 2; ++nt) {
          const int gn = n0 + wn + nt * 16 + l15;
          const float aval = acc[mt][nt][r];
          const float xo   = (float)xold[(size_t)gm * N + gn];
          pa  += aval;
          pxa += xo * aval;
          pxb += xo * bb[nt];
          float r01 = rng_u01(key, (uint32_t)(gm * N + gn));
          xnew[(size_t)gm * N + gn] = (f16)bern_fast(aval + bb[nt], r01);
        }
#pragma unroll
        for (int m = 1; m < 16; m <<= 1) {
          pa  += __shfl_xor(pa,  m, 64);
          pxa += __shfl_xor(pxa, m, 64);
          pxb += __shfl_xor(pxb, m, 64);
        }
        if (l15 == 0) {
          const int slot = blockIdx.y * 2 + (wave & 1);
          pA [(size_t)gm * 32 + slot] = pa;
          pXA[(size_t)gm * 32 + slot] = pxa;
          pXB[(size_t)gm * 32 + slot] = pxb;
        }
      }
  }
}

// -------- deferred u-recurrence: half-wave per row, coalesced reads ---------
// slabs: p[step][row][32]. Wave handles 2 rows (lane = r2*32 + slot).
__global__ __launch_bounds__(256) void u_chain(
    const float* __restrict__ pA, const float* __restrict__ pXA,
    const float* __restrict__ pXB, const float* __restrict__ bsum,
    const uint2* __restrict__ keys, float* __restrict__ u)
{
  const int t = threadIdx.x, wave = t >> 6, lane = t & 63;
  const int r2 = lane >> 5, slot = lane & 31;
  const int row = blockIdx.x * 8 + wave * 2 + r2;
  const float bs = bsum[0];
  float uo = u[row];                       // u0 (same in all 32 lanes)
  for (int s = 0; s < KSTEPS; ++s) {
    const size_t o = (size_t)s * 32 * Bn + (size_t)row * 32 + slot;
    float sa  = pA [o];
    float sxa = pXA[o];
    float sxb = pXB[o];
#pragma unroll
    for (int m = 1; m < 32; m <<= 1) {     // butterfly within the 32-lane half
      sa  += __shfl_xor(sa,  m, 64);
      sxa += __shfl_xor(sxa, m, 64);
      sxb += __shfl_xor(sxb, m, 64);
    }
    const float va = (uo > 0.5f) ? sxa : sa - sxa;
    const float vb = (uo > 0.5f) ? sxb : bs - sxb;
    const float dE = -bs - sa + 2.f * vb + 2.f * va;
    uo = bern_fast(dE, rng_u01(keys[2 + 3 * s], (uint32_t)row));
  }
  if (slot == 0) u[row] = uo;
}

// ------------------------------ free energy --------------------------------
__global__ __launch_bounds__(256) void fe_rows(
    const f16* __restrict__ araw, const f16* __restrict__ x,
    const float* __restrict__ u,
    const float* __restrict__ bvec, const float* __restrict__ cvec,
    const float* __restrict__ colsum, const float* __restrict__ bsum,
    float* __restrict__ Fout)
{
  __shared__ float s1[4], s2[4], s3[4];
  const int row = blockIdx.x;
  const int t = threadIdx.x;
  const float uo = u[row];
  const f16x4  a4 = *(const f16x4*)(araw + (size_t)row * Hn + t * 4);
  const float4 c4 = ((const float4*)cvec)[t];
  const float4 w4 = ((const float4*)colsum)[t];
  const float4 b4 = ((const float4*)bvec)[t];
  const f16x4  x4 = *(const f16x4*)(x + (size_t)row * Vn + t * 4);

  float aa[4] = { (float)a4[0], (float)a4[1], (float)a4[2], (float)a4[3] };
  float cc[4] = { c4.x, c4.y, c4.z, c4.w };
  float ww[4] = { w4.x, w4.y, w4.z, w4.w };
  float bb[4] = { b4.x, b4.y, b4.z, b4.w };
  float S1 = 0.f, S2 = 0.f, xb = 0.f;
#pragma unroll
  for (int j = 0; j < 4; ++j) {
    float m = (uo > 0.5f) ? aa[j] : ww[j] - aa[j];
    S1 += softplus_fast(m + cc[j]);
    S2 += softplus_fast(ww[j] - m + cc[j]);
    xb += (float)x4[j] * bb[j];
  }
#pragma unroll
  for (int off = 32; off > 0; off >>= 1) {
    S1 += __shfl_down(S1, off, 64);
    S2 += __shfl_down(S2, off, 64);
    xb += __shfl_down(xb, off, 64);
  }
  const int wv = t >> 6, ln = t & 63;
  if (ln == 0) { s1[wv] = S1; s2[wv] = S2; s3[wv] = xb; }
  __syncthreads();
  if (t == 0) {
    S1 = s1[0] + s1[1] + s1[2] + s1[3];
    S2 = s2[0] + s2[1] + s2[2] + s2[3];
    xb = s3[0] + s3[1] + s3[2] + s3[3];
    float vb = (uo > 0.5f) ? xb : bsum[0] - xb;
    float negn = vb - S1;
    float negf = (bsum[0] - vb) - S2;
    float mx = fmaxf(negn, negf);
    Fout[row] = -(mx + logf(expf(negn - mx) + expf(negf - mx)));
  }
}

__global__ __launch_bounds__(256) void finalize_k(
    const float* __restrict__ Fd, const float* __restrict__ Fm, float* __restrict__ out)
{
  __shared__ double sb[8];
  double sd = 0.0, sm = 0.0;
  for (int i = threadIdx.x; i < Bn; i += 256) { sd += (double)Fd[i]; sm += (double)Fm[i]; }
  for (int off = 32; off > 0; off >>= 1) { sd += __shfl_down(sd, off, 64); sm += __shfl_down(sm, off, 64); }
  const int wv = threadIdx.x >> 6, ln = threadIdx.x & 63;
  if (ln == 0) { sb[wv] = sd; sb[4 + wv] = sm; }
  __syncthreads();
  if (threadIdx.x == 0) {
    sd = sb[0] + sb[1] + sb[2] + sb[3];
    sm = sb[4] + sb[5] + sb[6] + sb[7];
    out[0] = (float)((sd - sm) / (double)Bn);
  }
}

// ------------------------------ launch glue --------------------------------
extern "C" void kernel_launch(void* const* d_in, const int* in_sizes, int n_in,
                              void* d_out, int out_size, void* d_ws, size_t ws_size,
                              hipStream_t stream) {
  const float* v_data = (const float*)d_in[0];
  const float* W      = (const float*)d_in[1];
  const float* bvec   = (const float*)d_in[2];
  const float* cvec   = (const float*)d_in[3];
  const int*   seedp  = (const int*)d_in[4];
  float* out = (float*)d_out;

  char* ws = (char*)d_ws;
  size_t off = 0;
  auto alloc = [&](size_t bytes) -> void* {
    void* p = ws + off;
    off += (bytes + 255) & ~(size_t)255;
    return p;
  };
  f16*   xb0  = (f16*)alloc((size_t)Bn * Vn * 2);     // 16 MB x ping
  f16*   xb1  = (f16*)alloc((size_t)Bn * Vn * 2);     // 16 MB x pong
  f16*   h    = (f16*)alloc((size_t)Bn * Hn * 2);     // 16 MB
  f16*   araw = (f16*)alloc((size_t)Bn * Hn * 2);     // 16 MB
  f16*   Wf   = (f16*)alloc((size_t)Vn * Hn * 2);     // 2 MB  [V][H]
  f16*   WTf  = (f16*)alloc((size_t)Vn * Hn * 2);     // 2 MB  [H][V]
  float* cpart  = (float*)alloc(64 * Hn * 4);
  float* colsum = (float*)alloc(Hn * 4);
  float* bsum   = (float*)alloc(256);
  uint2* keys   = (uint2*)alloc(64 * sizeof(uint2));
  float* u      = (float*)alloc(Bn * 4);
  float* pA     = (float*)alloc((size_t)KSTEPS * 32 * Bn * 4); // 10.5 MB
  float* pXA    = (float*)alloc((size_t)KSTEPS * 32 * Bn * 4);
  float* pXB    = (float*)alloc((size_t)KSTEPS * 32 * Bn * 4);
  float* Fd     = (float*)alloc(Bn * 4);
  float* Fm     = (float*)alloc(Bn * 4);
  (void)ws_size; (void)in_sizes; (void)n_in; (void)out_size;

  prep_keys<<<1, 64, 0, stream>>>(seedp, keys);
  colsum_part<<<64, 256, 0, stream>>>(W, cpart);
  colsum_red<<<4, 256, 0, stream>>>(cpart, colsum);
  bsum_k<<<1, 256, 0, stream>>>(bvec, bsum);
  cast_W<<<dim3(Hn / 64, Vn / 64), 256, 0, stream>>>(W, Wf, WTf);
  u0_init<<<Bn / 256, 256, 0, stream>>>(keys, u);
  cast_vx<<<(Bn * Vn / 4) / 256, 256, 0, stream>>>(v_data, u, xb0);

  dim3 gg(Bn / 64, Hn / 64);   // 2048 blocks = 8/CU
  f16* xs[2] = { xb0, xb1 };

  // step 0 fused with F(v_data): araw = x0@W (== v_branch@W), h sampled
  gemm_s<2><<<gg, 256, 0, stream>>>(xb0, WTf, araw, h, nullptr, nullptr,
                                    nullptr, cvec, nullptr, nullptr, nullptr, keys, 1);
  fe_rows<<<Bn, 256, 0, stream>>>(araw, xb0, u, bvec, cvec, colsum, bsum, Fd);

  for (int s = 0; s < KSTEPS; ++s) {
    if (s > 0) {
      gemm_s<1><<<gg, 256, 0, stream>>>(xs[s & 1], WTf, nullptr, h, nullptr,
                                        nullptr, nullptr, cvec, nullptr, nullptr,
                                        nullptr, keys, 1 + 3 * s);
    }
    const size_t so = (size_t)s * 32 * Bn;
    gemm_s<3><<<gg, 256, 0, stream>>>(h, Wf, nullptr, nullptr, xs[s & 1],
                                      xs[(s + 1) & 1], bvec, nullptr,
                                      pA + so, pXA + so, pXB + so, keys, 3 + 3 * s);
  }

  // F(v_model) gemm (u-independent), then the whole u-chain in one launch
  gemm_s<0><<<gg, 256, 0, stream>>>(xs[KSTEPS & 1], WTf, araw, nullptr, nullptr,
                                    nullptr, nullptr, nullptr, nullptr, nullptr,
                                    nullptr, keys, 0);
  u_chain<<<Bn / 8, 256, 0, stream>>>(pA, pXA, pXB, bsum, keys, u);
  fe_rows<<<Bn, 256, 0, stream>>>(araw, xs[KSTEPS & 1], u, bvec, cvec, colsum, bsum, Fm);

  finalize_k<<<1, 256, 0, stream>>>(Fd, Fm, out);
}

// Round 17
// 941.022 us; speedup vs baseline: 1.1786x; 1.0066x over previous
//
#include <hip/hip_runtime.h>
#include <hip/hip_bf16.h>
#include <stdint.h>
#include <math.h>

// ---------------------------------------------------------------------------
// SymmetricRBM: CD loss, 10-step Gibbs, JAX-threefry-exact RNG.
// B=8192, V=H=1024. R16->R17: algebraic epilogue fusion.
//  - Sum(a) = Sum_k h_k colsum_k and Sum(x*a) = Sum_k h_k M_k  -> pA/pXA
//    partials move into the EPI1 h-sampling epilogue (h, M both in regs);
//    EPI3 drops its 16 MB xold read (now: sample x_new + emit x_new.b only).
//  - Free energy fused into gemm epilogues: SA=Sum sp(M+c), SB=Sum sp(colsum
//    -M+c) are u-independent (u just SWAPS them), emitted per-slot by
//    EPI2/EPI4; araw (2x16MB W + 32MB R) and both fe_rows kernels deleted;
//    tiny fe_finish computes Fd,Fm at the end.
// gemm core frozen (R12: 64x64xBK64, 8 blocks/CU, 0 conflicts).
// ---------------------------------------------------------------------------

static constexpr int Bn = 8192;
static constexpr int Vn = 1024;
static constexpr int Hn = 1024;
static constexpr int KSTEPS = 10;

typedef _Float16 f16;
typedef f16   f16x4 __attribute__((ext_vector_type(4)));
typedef f16   f16x8 __attribute__((ext_vector_type(8)));
typedef float f32x4 __attribute__((ext_vector_type(4)));

#define GLOBAL_LOAD_LDS16(g, l)                                              \
  __builtin_amdgcn_global_load_lds(                                          \
      (const __attribute__((address_space(1))) uint32_t*)(g),                \
      (__attribute__((address_space(3))) uint32_t*)(l), 16, 0, 0)

// ------------------------- Threefry-2x32 (JAX-exact) -----------------------
__device__ __forceinline__ uint32_t rotl32(uint32_t x, int d) {
  return (x << d) | (x >> (32 - d));
}

__device__ __forceinline__ void tf2x32(uint32_t k0, uint32_t k1,
                                       uint32_t x0, uint32_t x1,
                                       uint32_t& o0, uint32_t& o1) {
  uint32_t k2 = k0 ^ k1 ^ 0x1BD11BDAu;
#define TFR(r) { x0 += x1; x1 = rotl32(x1, (r)); x1 ^= x0; }
  x0 += k0; x1 += k1;
  TFR(13) TFR(15) TFR(26) TFR(6)
  x0 += k1; x1 += k2 + 1u;
  TFR(17) TFR(29) TFR(16) TFR(24)
  x0 += k2; x1 += k0 + 2u;
  TFR(13) TFR(15) TFR(26) TFR(6)
  x0 += k0; x1 += k1 + 3u;
  TFR(17) TFR(29) TFR(16) TFR(24)
  x0 += k1; x1 += k2 + 4u;
  TFR(13) TFR(15) TFR(26) TFR(6)
  x0 += k2; x1 += k0 + 5u;
#undef TFR
  o0 = x0; o1 = x1;
}

__device__ __forceinline__ float rng_u01(uint2 key, uint32_t idx) {
  uint32_t o0, o1;
  tf2x32(key.x, key.y, 0u, idx, o0, o1);
  uint32_t bits = o0 ^ o1;
  return __uint_as_float((bits >> 9) | 0x3F800000u) - 1.0f;
}

// fast Bernoulli accept: r01 < sigmoid(z)  <=>  r01*(1+exp(-z)) < 1
__device__ __forceinline__ float bern_fast(float z, float r01) {
  float e = __expf(-z);
  return (__builtin_fmaf(r01, e, r01) < 1.0f) ? 1.f : 0.f;
}
__device__ __forceinline__ float softplus_fast(float x) {
  return fmaxf(x, 0.f) + __logf(1.f + __expf(-fabsf(x)));
}

// ------------------------------- prep kernels ------------------------------
__global__ void prep_keys(const int* __restrict__ seedp, uint2* __restrict__ keys) {
  if (threadIdx.x != 0 || blockIdx.x != 0) return;
  uint32_t seed = (uint32_t)(*seedp);
  uint2 key = make_uint2(0u, seed);
  uint2 nk, kk;
  tf2x32(key.x, key.y, 0u, 0u, nk.x, nk.y);
  tf2x32(key.x, key.y, 0u, 1u, kk.x, kk.y);
  keys[0] = kk;   // k0
  key = nk;
  for (int s = 0; s < KSTEPS; ++s) {
    uint2 t0, t1, t2, t3;
    tf2x32(key.x, key.y, 0u, 0u, t0.x, t0.y);
    tf2x32(key.x, key.y, 0u, 1u, t1.x, t1.y);
    tf2x32(key.x, key.y, 0u, 2u, t2.x, t2.y);
    tf2x32(key.x, key.y, 0u, 3u, t3.x, t3.y);
    key = t0;
    keys[1 + 3*s] = t1;  // k1
    keys[2 + 3*s] = t2;  // k2
    keys[3 + 3*s] = t3;  // k3
  }
}

__global__ __launch_bounds__(256) void colsum_part(
    const float* __restrict__ W, float* __restrict__ part) {
  const int bx = blockIdx.x, t = threadIdx.x;
  float s0 = 0.f, s1 = 0.f, s2 = 0.f, s3 = 0.f;
#pragma unroll
  for (int r = 0; r < 16; ++r) {
    const float* row = W + (size_t)(bx * 16 + r) * Hn;
    s0 += row[t]; s1 += row[t + 256]; s2 += row[t + 512]; s3 += row[t + 768];
  }
  float* p = part + (size_t)bx * Hn;
  p[t] = s0; p[t + 256] = s1; p[t + 512] = s2; p[t + 768] = s3;
}

__global__ __launch_bounds__(256) void colsum_red(
    const float* __restrict__ part, float* __restrict__ cs) {
  const int col = blockIdx.x * 256 + threadIdx.x;
  float s = 0.f;
#pragma unroll
  for (int k = 0; k < 64; ++k) s += part[(size_t)k * Hn + col];
  cs[col] = s;
}

__global__ void bsum_k(const float* __restrict__ bvec, float* __restrict__ bs) {
  __shared__ float sb[4];
  float s = 0.f;
  for (int i = threadIdx.x; i < Vn; i += 256) s += bvec[i];
  for (int off = 32; off > 0; off >>= 1) s += __shfl_down(s, off, 64);
  int wv = threadIdx.x >> 6, ln = threadIdx.x & 63;
  if (ln == 0) sb[wv] = s;
  __syncthreads();
  if (threadIdx.x == 0) bs[0] = sb[0] + sb[1] + sb[2] + sb[3];
}

__global__ __launch_bounds__(256) void cast_W(
    const float* __restrict__ W, f16* __restrict__ Wf, f16* __restrict__ WTf) {
  __shared__ f16 tile[64][65];
  const int j0 = blockIdx.x * 64, i0 = blockIdx.y * 64;
  const int tx = threadIdx.x & 63, tg = threadIdx.x >> 6;
#pragma unroll 4
  for (int rr = 0; rr < 16; ++rr) {
    const int row = tg * 16 + rr;
    float w = W[(size_t)(i0 + row) * Hn + j0 + tx];
    f16 hw = (f16)w;
    Wf[(size_t)(i0 + row) * Hn + j0 + tx] = hw;
    tile[row][tx] = hw;
  }
  __syncthreads();
#pragma unroll 4
  for (int rr = 0; rr < 16; ++rr) {
    const int row = tg * 16 + rr;
    WTf[(size_t)(j0 + row) * Vn + i0 + tx] = tile[tx][row];
  }
}

__global__ void u0_init(const uint2* __restrict__ keys, float* __restrict__ u0) {
  int b = blockIdx.x * 256 + threadIdx.x;
  float r01 = rng_u01(keys[0], (uint32_t)b);
  u0[b] = (r01 < 0.5f) ? 1.f : 0.f;
}

// x0 = u0 ? v_data : 1-v_data; also emit pXB[0][row][slot] = Sum x0*b (32 cols)
__global__ __launch_bounds__(256) void cast_vx(
    const float* __restrict__ vd, const float* __restrict__ u0,
    const float* __restrict__ bvec, f16* __restrict__ x,
    float* __restrict__ pXB0) {
  const int row = blockIdx.x;                       // 1 row per block
  const int t = threadIdx.x;                        // cols 4t..4t+3
  const float uo = u0[row];
  const float4 d  = ((const float4*)(vd + (size_t)row * Vn))[t];
  const float4 bv = ((const float4*)bvec)[t];
  float xv[4] = { d.x, d.y, d.z, d.w };
  if (uo <= 0.5f) { xv[0]=1.f-xv[0]; xv[1]=1.f-xv[1]; xv[2]=1.f-xv[2]; xv[3]=1.f-xv[3]; }
  f16x4 o = { (f16)xv[0], (f16)xv[1], (f16)xv[2], (f16)xv[3] };
  *(f16x4*)(x + (size_t)row * Vn + t * 4) = o;
  float xb = xv[0]*bv.x + xv[1]*bv.y + xv[2]*bv.z + xv[3]*bv.w;
#pragma unroll
  for (int m = 1; m < 8; m <<= 1) xb += __shfl_xor(xb, m, 64);
  if ((t & 7) == 0) pXB0[(size_t)row * 32 + (t >> 3)] = xb;
}

// ------------------------- GEMM: 64x64 max-occupancy ------------------------
// Core frozen from R12. slot = blockIdx.y*2 + (wave&1)  (32 slots of 32 cols).
// EPI 1: h=Bern(sig(M+c)); pA = Sum h*colsum, pXA = Sum h*M per slot.
// EPI 2: EPI1 + free-energy partials SA = Sum sp(M+c), SB = Sum sp(colsum-M+c).
// EPI 3: x_new=Bern(sig(C+b)); pXBn = Sum x_new*b per slot (next step's dE).
// EPI 4: SA/SB partials only (final F(v_model) gemm).
template <int EPI>
__global__ __launch_bounds__(256, 8) void gemm_s(
    const f16* __restrict__ A, const f16* __restrict__ Bm,
    f16* __restrict__ outH, f16* __restrict__ xnew,
    const float* __restrict__ bvec, const float* __restrict__ cvec,
    const float* __restrict__ colsum,
    float* __restrict__ pA, float* __restrict__ pXA, float* __restrict__ pXBn,
    float* __restrict__ pSA, float* __restrict__ pSB,
    const uint2* __restrict__ keys, int keyIdx)
{
  constexpr int N = 1024, K = 1024, BK = 64;
  __shared__ alignas(16) f16 As[64 * BK];   // 8 KB
  __shared__ alignas(16) f16 Bs[64 * BK];   // 8 KB

  const int t = threadIdx.x, wave = t >> 6, lane = t & 63;
  const int l15 = lane & 15, quad = lane >> 4;
  const int m0 = blockIdx.x * 64, n0 = blockIdx.y * 64;
  const int wm = (wave >> 1) * 32, wn = (wave & 1) * 32;

  const int rbase = lane >> 3;
  const int gch   = (lane & 7) ^ rbase;
  const f16* gA = A  + (size_t)(m0 + wave * 16 + rbase) * K + gch * 8;
  const f16* gB = Bm + (size_t)(n0 + wave * 16 + rbase) * K + gch * 8;
  f16* lA = As + wave * 16 * BK;
  f16* lB = Bs + wave * 16 * BK;

  const int swz = l15 & 7;
  const int oA  = (wm + l15) * BK;
  const int oB  = (wn + l15) * BK;

  f32x4 acc[2][2] = {};

  for (int k0 = 0; k0 < K; k0 += BK) {
    GLOBAL_LOAD_LDS16(gA + k0,         lA);
    GLOBAL_LOAD_LDS16(gA + k0 + 8 * K, lA + 8 * BK);
    GLOBAL_LOAD_LDS16(gB + k0,         lB);
    GLOBAL_LOAD_LDS16(gB + k0 + 8 * K, lB + 8 * BK);
    __syncthreads();

#pragma unroll
    for (int kc = 0; kc < 2; ++kc) {
      const int fc = ((kc * 4 + quad) ^ swz) * 8;
      f16x8 af[2], bf[2];
#pragma unroll
      for (int i = 0; i < 2; ++i) {
        af[i] = *(const f16x8*)(&As[oA + i * 16 * BK + fc]);
        bf[i] = *(const f16x8*)(&Bs[oB + i * 16 * BK + fc]);
      }
#pragma unroll
      for (int mt = 0; mt < 2; ++mt)
#pragma unroll
        for (int nt = 0; nt < 2; ++nt)
          acc[mt][nt] = __builtin_amdgcn_mfma_f32_16x16x32_f16(af[mt], bf[nt], acc[mt][nt], 0, 0, 0);
    }
    __syncthreads();
  }

  // epilogue: C/D layout col = lane&15, row = quad*4 + reg   (m89/m91)
  const int slot = blockIdx.y * 2 + (wave & 1);

  if constexpr (EPI == 1 || EPI == 2) {
    const uint2 key = keys[keyIdx];
    float csv[2], cvv[2];
#pragma unroll
    for (int nt = 0; nt < 2; ++nt) {
      const int gn = n0 + wn + nt * 16 + l15;
      csv[nt] = colsum[gn];
      cvv[nt] = cvec[gn];
    }
#pragma unroll
    for (int mt = 0; mt < 2; ++mt)
#pragma unroll
      for (int r = 0; r < 4; ++r) {
        const int gm = m0 + wm + mt * 16 + quad * 4 + r;
        float pa = 0.f, pxa = 0.f, sa = 0.f, sb = 0.f;
#pragma unroll
        for (int nt = 0; nt < 2; ++nt) {
          const int gn = n0 + wn + nt * 16 + l15;
          const float val = acc[mt][nt][r];            // M = x@W
          float r01 = rng_u01(key, (uint32_t)(gm * N + gn));
          float hq  = bern_fast(val + cvv[nt], r01);
          outH[(size_t)gm * N + gn] = (f16)hq;
          pa  += hq * csv[nt];
          pxa += hq * val;
          if constexpr (EPI == 2) {
            sa += softplus_fast(val + cvv[nt]);
            sb += softplus_fast(csv[nt] - val + cvv[nt]);
          }
        }
#pragma unroll
        for (int m = 1; m < 16; m <<= 1) {
          pa  += __shfl_xor(pa,  m, 64);
          pxa += __shfl_xor(pxa, m, 64);
          if constexpr (EPI == 2) {
            sa += __shfl_xor(sa, m, 64);
            sb += __shfl_xor(sb, m, 64);
          }
        }
        if (l15 == 0) {
          pA [(size_t)gm * 32 + slot] = pa;
          pXA[(size_t)gm * 32 + slot] = pxa;
          if constexpr (EPI == 2) {
            pSA[(size_t)gm * 32 + slot] = sa;
            pSB[(size_t)gm * 32 + slot] = sb;
          }
        }
      }
  } else if constexpr (EPI == 3) {
    const uint2 key = keys[keyIdx];
    float bb[2];
#pragma unroll
    for (int nt = 0; nt < 2; ++nt) bb[nt] = bvec[n0 + wn + nt * 16 + l15];
#pragma unroll
    for (int mt = 0; mt < 2; ++mt)
#pragma unroll
      for (int r = 0; r < 4; ++r) {
        const int gm = m0 + wm + mt * 16 + quad * 4 + r;
        float pxb = 0.f;
#pragma unroll
        for (int nt = 0; nt < 2; ++nt) {
          const int gn = n0 + wn + nt * 16 + l15;
          const float aval = acc[mt][nt][r];
          float r01 = rng_u01(key, (uint32_t)(gm * N + gn));
          float xq  = bern_fast(aval + bb[nt], r01);
          xnew[(size_t)gm * N + gn] = (f16)xq;
          pxb += xq * bb[nt];
        }
#pragma unroll
        for (int m = 1; m < 16; m <<= 1) pxb += __shfl_xor(pxb, m, 64);
        if (l15 == 0) pXBn[(size_t)gm * 32 + slot] = pxb;
      }
  } else {
    // EPI 4: free-energy partials only
    float csv[2], cvv[2];
#pragma unroll
    for (int nt = 0; nt < 2; ++nt) {
      const int gn = n0 + wn + nt * 16 + l15;
      csv[nt] = colsum[gn];
      cvv[nt] = cvec[gn];
    }
#pragma unroll
    for (int mt = 0; mt < 2; ++mt)
#pragma unroll
      for (int r = 0; r < 4; ++r) {
        const int gm = m0 + wm + mt * 16 + quad * 4 + r;
        float sa = 0.f, sb = 0.f;
#pragma unroll
        for (int nt = 0; nt < 2; ++nt) {
          const float val = acc[mt][nt][r];
          sa += softplus_fast(val + cvv[nt]);
          sb += softplus_fast(csv[nt] - val + cvv[nt]);
        }
#pragma unroll
        for (int m = 1; m < 16; m <<= 1) {
          sa += __shfl_xor(sa, m, 64);
          sb += __shfl_xor(sb, m, 64);
        }
        if (l15 == 0) {
          pSA[(size_t)gm * 32 + slot] = sa;
          pSB[(size_t)gm * 32 + slot] = sb;
        }
      }
  }
}

// -------- deferred u-recurrence: half-wave per row, coalesced reads ---------
__global__ __launch_bounds__(256) void u_chain(
    const float* __restrict__ pA, const float* __restrict__ pXA,
    const float* __restrict__ pXB, const float* __restrict__ bsum,
    const uint2* __restrict__ keys, const float* __restrict__ u0,
    float* __restrict__ uF)
{
  const int t = threadIdx.x, wave = t >> 6, lane = t & 63;
  const int r2 = lane >> 5, slot = lane & 31;
  const int row = blockIdx.x * 8 + wave * 2 + r2;
  const float bs = bsum[0];
  float uo = u0[row];
  for (int s = 0; s < KSTEPS; ++s) {
    const size_t o = (size_t)s * 32 * Bn + (size_t)row * 32 + slot;
    float sa  = pA [o];
    float sxa = pXA[o];
    float sxb = pXB[o];
#pragma unroll
    for (int m = 1; m < 32; m <<= 1) {
      sa  += __shfl_xor(sa,  m, 64);
      sxa += __shfl_xor(sxa, m, 64);
      sxb += __shfl_xor(sxb, m, 64);
    }
    const float va = (uo > 0.5f) ? sxa : sa - sxa;
    const float vb = (uo > 0.5f) ? sxb : bs - sxb;
    const float dE = -bs - sa + 2.f * vb + 2.f * va;
    uo = bern_fast(dE, rng_u01(keys[2 + 3 * s], (uint32_t)row));
  }
  if (slot == 0) uF[row] = uo;
}

// ---------------- fused free energy finish (Fd and Fm) ----------------------
__device__ __forceinline__ float fe_eval(float SA, float SB, float xb,
                                         float uo, float bs) {
  float S1 = (uo > 0.5f) ? SA : SB;
  float S2 = (uo > 0.5f) ? SB : SA;
  float vb = (uo > 0.5f) ? xb : bs - xb;
  float negn = vb - S1;
  float negf = (bs - vb) - S2;
  float mx = fmaxf(negn, negf);
  return -(mx + logf(expf(negn - mx) + expf(negf - mx)));
}

__global__ __launch_bounds__(256) void fe_finish(
    const float* __restrict__ SA0, const float* __restrict__ SB0,
    const float* __restrict__ xb0,
    const float* __restrict__ SAF, const float* __restrict__ SBF,
    const float* __restrict__ xbF,
    const float* __restrict__ u0, const float* __restrict__ uF,
    const float* __restrict__ bsum,
    float* __restrict__ Fd, float* __restrict__ Fm)
{
  const int t = threadIdx.x, wave = t >> 6, lane = t & 63;
  const int r2 = lane >> 5, slot = lane & 31;
  const int row = blockIdx.x * 8 + wave * 2 + r2;
  const size_t o = (size_t)row * 32 + slot;
  const float bs = bsum[0];
  float a0 = SA0[o], b0 = SB0[o], x0 = xb0[o];
  float aF = SAF[o], bF = SBF[o], xF = xbF[o];
#pragma unroll
  for (int m = 1; m < 32; m <<= 1) {
    a0 += __shfl_xor(a0, m, 64);  b0 += __shfl_xor(b0, m, 64);
    x0 += __shfl_xor(x0, m, 64);  aF += __shfl_xor(aF, m, 64);
    bF += __shfl_xor(bF, m, 64);  xF += __shfl_xor(xF, m, 64);
  }
  if (slot == 0) {
    Fd[row] = fe_eval(a0, b0, x0, u0[row], bs);
    Fm[row] = fe_eval(aF, bF, xF, uF[row], bs);
  }
}

__global__ __launch_bounds__(256) void finalize_k(
    const float* __restrict__ Fd, const float* __restrict__ Fm, float* __restrict__ out)
{
  __shared__ double sb[8];
  double sd = 0.0, sm = 0.0;
  for (int i = threadIdx.x; i < Bn; i += 256) { sd += (double)Fd[i]; sm += (double)Fm[i]; }
  for (int off = 32; off > 0; off >>= 1) { sd += __shfl_down(sd, off, 64); sm += __shfl_down(sm, off, 64); }
  const int wv = threadIdx.x >> 6, ln = threadIdx.x & 63;
  if (ln == 0) { sb[wv] = sd; sb[4 + wv] = sm; }
  __syncthreads();
  if (threadIdx.x == 0) {
    sd = sb[0] + sb[1] + sb[2] + sb[3];
    sm = sb[4] + sb[5] + sb[6] + sb[7];
    out[0] = (float)((sd - sm) / (double)Bn);
  }
}

// ------------------------------ launch glue --------------------------------
extern "C" void kernel_launch(void* const* d_in, const int* in_sizes, int n_in,
                              void* d_out, int out_size, void* d_ws, size_t ws_size,
                              hipStream_t stream) {
  const float* v_data = (const float*)d_in[0];
  const float* W      = (const float*)d_in[1];
  const float* bvec   = (const float*)d_in[2];
  const float* cvec   = (const float*)d_in[3];
  const int*   seedp  = (const int*)d_in[4];
  float* out = (float*)d_out;

  char* ws = (char*)d_ws;
  size_t off = 0;
  auto alloc = [&](size_t bytes) -> void* {
    void* p = ws + off;
    off += (bytes + 255) & ~(size_t)255;
    return p;
  };
  f16*   xb0  = (f16*)alloc((size_t)Bn * Vn * 2);     // 16 MB x ping
  f16*   xb1  = (f16*)alloc((size_t)Bn * Vn * 2);     // 16 MB x pong
  f16*   h    = (f16*)alloc((size_t)Bn * Hn * 2);     // 16 MB
  f16*   Wf   = (f16*)alloc((size_t)Vn * Hn * 2);     // 2 MB  [V][H]
  f16*   WTf  = (f16*)alloc((size_t)Vn * Hn * 2);     // 2 MB  [H][V]
  float* cpart  = (float*)alloc(64 * Hn * 4);
  float* colsum = (float*)alloc(Hn * 4);
  float* bsum   = (float*)alloc(256);
  uint2* keys   = (uint2*)alloc(64 * sizeof(uint2));
  float* u0     = (float*)alloc(Bn * 4);
  float* uF     = (float*)alloc(Bn * 4);
  float* pA     = (float*)alloc((size_t)KSTEPS * 32 * Bn * 4);        // 10 MB
  float* pXA    = (float*)alloc((size_t)KSTEPS * 32 * Bn * 4);        // 10 MB
  float* pXB    = (float*)alloc((size_t)(KSTEPS + 1) * 32 * Bn * 4);  // 11 MB
  float* SA0    = (float*)alloc((size_t)32 * Bn * 4);                 // 1 MB
  float* SB0    = (float*)alloc((size_t)32 * Bn * 4);
  float* SAF    = (float*)alloc((size_t)32 * Bn * 4);
  float* SBF    = (float*)alloc((size_t)32 * Bn * 4);
  float* Fd     = (float*)alloc(Bn * 4);
  float* Fm     = (float*)alloc(Bn * 4);
  (void)ws_size; (void)in_sizes; (void)n_in; (void)out_size;

  prep_keys<<<1, 64, 0, stream>>>(seedp, keys);
  colsum_part<<<64, 256, 0, stream>>>(W, cpart);
  colsum_red<<<4, 256, 0, stream>>>(cpart, colsum);
  bsum_k<<<1, 256, 0, stream>>>(bvec, bsum);
  cast_W<<<dim3(Hn / 64, Vn / 64), 256, 0, stream>>>(W, Wf, WTf);
  u0_init<<<Bn / 256, 256, 0, stream>>>(keys, u0);
  cast_vx<<<Bn, 256, 0, stream>>>(v_data, u0, bvec, xb0, pXB);   // pXB slab 0

  dim3 gg(Bn / 64, Hn / 64);   // 2048 blocks = 8/CU
  f16* xs[2] = { xb0, xb1 };
  const size_t SL = (size_t)32 * Bn;

  for (int s = 0; s < KSTEPS; ++s) {
    // M = x_s@W -> h sampled; pA/pXA slab s; step 0 also emits SA0/SB0 (Fd)
    if (s == 0) {
      gemm_s<2><<<gg, 256, 0, stream>>>(xs[0], WTf, h, nullptr, nullptr, cvec,
                                        colsum, pA, pXA, nullptr, SA0, SB0,
                                        keys, 1);
    } else {
      gemm_s<1><<<gg, 256, 0, stream>>>(xs[s & 1], WTf, h, nullptr, nullptr, cvec,
                                        colsum, pA + (size_t)s * SL,
                                        pXA + (size_t)s * SL, nullptr,
                                        nullptr, nullptr, keys, 1 + 3 * s);
    }
    // a = h@W^T -> x_{s+1} sampled; pXB slab s+1
    gemm_s<3><<<gg, 256, 0, stream>>>(h, Wf, nullptr, xs[(s + 1) & 1], bvec,
                                      nullptr, nullptr, nullptr, nullptr,
                                      pXB + (size_t)(s + 1) * SL,
                                      nullptr, nullptr, keys, 3 + 3 * s);
  }

  // F(v_model) partials: M = x10@W -> SAF/SBF
  gemm_s<4><<<gg, 256, 0, stream>>>(xs[KSTEPS & 1], WTf, nullptr, nullptr,
                                    nullptr, cvec, colsum, nullptr, nullptr,
                                    nullptr, SAF, SBF, keys, 0);

  u_chain<<<Bn / 8, 256, 0, stream>>>(pA, pXA, pXB, bsum, keys, u0, uF);
  fe_finish<<<Bn / 8, 256, 0, stream>>>(SA0, SB0, pXB,
                                        SAF, SBF, pXB + (size_t)KSTEPS * SL,
                                        u0, uF, bsum, Fd, Fm);
  finalize_k<<<1, 256, 0, stream>>>(Fd, Fm, out);
}